// Round 4
// baseline (6704.235 us; speedup 1.0000x reference)
//
#include <hip/hip_runtime.h>
#include <hip/hip_bf16.h>

#define HID   512
#define SEQ   1024
#define WGD   32          // workgroups per LSTM direction
#define GATES 2048        // 4*HID

// ---------------------------------------------------------------- helpers
__device__ __forceinline__ float sigm(float x) {
    return 1.f / (1.f + __expf(-x));
}
__device__ __forceinline__ float tanh_fast(float x) {
    float ax = fabsf(x);
    float e  = __expf(-2.f * ax);
    float t  = (1.f - e) * __builtin_amdgcn_rcpf(1.f + e);
    return copysignf(t, x);
}

// ---------------------------------------------------------------- embedding
__global__ void embed_kernel(const int* __restrict__ wi, const int* __restrict__ pi,
                             const float* __restrict__ we, const float* __restrict__ pe,
                             float* __restrict__ x) {
    int i = blockIdx.x;          // token 0..1023
    int t = threadIdx.x;         // 128 threads
    const float* w = we + (size_t)wi[i] * 300;
    const float* p = pe + (size_t)pi[i] * 100;
    float* xo = x + (size_t)i * 400;
    for (int c = t; c < 300; c += 128) xo[c]       = w[c];
    for (int c = t; c < 100; c += 128) xo[300 + c] = p[c];
}

// ---------------------------------------------------------------- fp32 GEMM: C[M,N] = A[M,K] @ B[N,K]^T + bias[N]
__global__ __launch_bounds__(256)
void gemm_bias(const float* __restrict__ A, const float* __restrict__ B,
               const float* __restrict__ bias, float* __restrict__ C,
               int M, int N, int K, int lda, int ldb, int ldc) {
    __shared__ float As[64 * 17];
    __shared__ float Bs[64 * 17];
    const int tid  = threadIdx.x;
    const int bn   = blockIdx.x, bm = blockIdx.y;
    const int tj   = tid & 15, ti = tid >> 4;
    const int lrow = tid >> 2;
    const int lk4  = (tid & 3) << 2;
    float acc[4][4] = {};

    for (int kt = 0; kt < K; kt += 16) {
        float4 av = *(const float4*)(A + (size_t)(bm * 64 + lrow) * lda + kt + lk4);
        float4 bv = *(const float4*)(B + (size_t)(bn * 64 + lrow) * ldb + kt + lk4);
        As[lrow * 17 + lk4 + 0] = av.x; As[lrow * 17 + lk4 + 1] = av.y;
        As[lrow * 17 + lk4 + 2] = av.z; As[lrow * 17 + lk4 + 3] = av.w;
        Bs[lrow * 17 + lk4 + 0] = bv.x; Bs[lrow * 17 + lk4 + 1] = bv.y;
        Bs[lrow * 17 + lk4 + 2] = bv.z; Bs[lrow * 17 + lk4 + 3] = bv.w;
        __syncthreads();
        #pragma unroll
        for (int k = 0; k < 16; ++k) {
            float a0 = As[(ti * 4 + 0) * 17 + k];
            float a1 = As[(ti * 4 + 1) * 17 + k];
            float a2 = As[(ti * 4 + 2) * 17 + k];
            float a3 = As[(ti * 4 + 3) * 17 + k];
            float b0 = Bs[(tj * 4 + 0) * 17 + k];
            float b1 = Bs[(tj * 4 + 1) * 17 + k];
            float b2_ = Bs[(tj * 4 + 2) * 17 + k];
            float b3 = Bs[(tj * 4 + 3) * 17 + k];
            acc[0][0] = fmaf(a0, b0, acc[0][0]); acc[0][1] = fmaf(a0, b1, acc[0][1]);
            acc[0][2] = fmaf(a0, b2_, acc[0][2]); acc[0][3] = fmaf(a0, b3, acc[0][3]);
            acc[1][0] = fmaf(a1, b0, acc[1][0]); acc[1][1] = fmaf(a1, b1, acc[1][1]);
            acc[1][2] = fmaf(a1, b2_, acc[1][2]); acc[1][3] = fmaf(a1, b3, acc[1][3]);
            acc[2][0] = fmaf(a2, b0, acc[2][0]); acc[2][1] = fmaf(a2, b1, acc[2][1]);
            acc[2][2] = fmaf(a2, b2_, acc[2][2]); acc[2][3] = fmaf(a2, b3, acc[2][3]);
            acc[3][0] = fmaf(a3, b0, acc[3][0]); acc[3][1] = fmaf(a3, b1, acc[3][1]);
            acc[3][2] = fmaf(a3, b2_, acc[3][2]); acc[3][3] = fmaf(a3, b3, acc[3][3]);
        }
        __syncthreads();
    }
    const int n0 = bn * 64 + tj * 4;
    float bb0 = 0.f, bb1 = 0.f, bb2 = 0.f, bb3 = 0.f;
    if (bias) { bb0 = bias[n0]; bb1 = bias[n0 + 1]; bb2 = bias[n0 + 2]; bb3 = bias[n0 + 3]; }
    #pragma unroll
    for (int i = 0; i < 4; ++i) {
        float4 o;
        o.x = acc[i][0] + bb0; o.y = acc[i][1] + bb1;
        o.z = acc[i][2] + bb2; o.w = acc[i][3] + bb3;
        *(float4*)(C + (size_t)(bm * 64 + ti * 4 + i) * ldc + n0) = o;
    }
}

// ---------------------------------------------------------------- persistent bidirectional LSTM layer
// 64 WGs x 512 threads. WGs [0,32): forward; [32,64): reverse.
// Each WAVE owns 2 complete hidden units (8 full gate rows, K=512):
//   lane l holds Whh[row][c*64+l] (c=0..7, 64 weights) and h[c*64+l],
//   so the matvec is 64 lane-private fmas (no readlane), then one 6-stage
//   x8 shfl_xor butterfly gives full dots in every lane. Lanes 0..1 compute
//   gates and publish their unit immediately. NO __syncthreads in the loop.
// Only wave 0 polls global tags (h as (tag<<32|bits) relaxed AGENT atomics);
// it relays h via a double-buffered LDS slab + release/acquire LDS flag.
// Slab reuse at step s+2 is safe: global tag gating means all waves finished
// step s+1 (hence read slab(s)) before the poller can pass its s+2 poll.
__global__ __launch_bounds__(512)
void lstm_layer(const float* __restrict__ Zf, const float* __restrict__ Zr,
                const float* __restrict__ WhhF, const float* __restrict__ WhhR,
                unsigned long long* __restrict__ Hpair, // [SEQ][2*HID] (tag|h)
                float* __restrict__ Hout,               // [SEQ][2*HID] plain fp32
                unsigned tagBase) {
    const int dir = blockIdx.x >> 5;
    const int wg  = blockIdx.x & 31;
    const float* __restrict__ Z   = dir ? Zr   : Zf;
    const float* __restrict__ Whh = dir ? WhhR : WhhF;
    const int colOff = dir ? HID : 0;

    const int tid  = threadIdx.x;
    const int wave = tid >> 6;        // 0..7
    const int lane = tid & 63;
    const int Ub   = wg * 16 + wave * 2;   // first of this wave's 2 units

    // lane-private weights: w[j][c] = Whh[(j&3)*512 + Ub + (j>>2)][c*64+lane]
    float w[8][8];
    #pragma unroll
    for (int j = 0; j < 8; ++j) {
        const int row = (j & 3) * HID + Ub + (j >> 2);
        const float* wp = Whh + (size_t)row * HID + lane;
        #pragma unroll
        for (int c = 0; c < 8; ++c) w[j][c] = wp[c * 64];
    }

    __shared__ float hbuf[2][512];
    __shared__ int   flag;
    if (tid == 0) flag = 0;
    __syncthreads();

    float cval = 0.f;    // cell state of unit Ub+lane (lanes 0..1 only)

    for (int s = 0; s < SEQ; ++s) {
        const int t = dir ? (SEQ - 1 - s) : s;

        // prefetch z for this step's epilogue (lanes 0,1) — overlaps the wait
        float z0 = 0.f, z1 = 0.f, z2 = 0.f, z3 = 0.f;
        if (lane < 2) {
            const float* zp = Z + (size_t)t * GATES + Ub + lane;
            z0 = zp[0]; z1 = zp[512]; z2 = zp[1024]; z3 = zp[1536];
        }

        float h[8];
        if (s > 0) {
            float* slab = hbuf[s & 1];
            if (wave == 0) {
                const int tp = dir ? (t + 1) : (t - 1);
                const unsigned expTag = tagBase + (unsigned)s - 1u;
                const unsigned long long* hp = Hpair + (size_t)tp * (2 * HID) + colOff;
                unsigned long long v[8];
                for (;;) {
                    #pragma unroll
                    for (int c = 0; c < 8; ++c)
                        v[c] = __hip_atomic_load(hp + c * 64 + lane, __ATOMIC_RELAXED, __HIP_MEMORY_SCOPE_AGENT);
                    int ok = 1;
                    #pragma unroll
                    for (int c = 0; c < 8; ++c) ok &= ((unsigned)(v[c] >> 32) == expTag);
                    if (__all(ok)) break;
                }
                #pragma unroll
                for (int c = 0; c < 8; ++c) {
                    h[c] = __uint_as_float((unsigned)v[c]);
                    slab[c * 64 + lane] = h[c];
                }
                __hip_atomic_store(&flag, s, __ATOMIC_RELEASE, __HIP_MEMORY_SCOPE_WORKGROUP);
            } else {
                while (__hip_atomic_load(&flag, __ATOMIC_ACQUIRE, __HIP_MEMORY_SCOPE_WORKGROUP) < s) {}
                #pragma unroll
                for (int c = 0; c < 8; ++c) h[c] = slab[c * 64 + lane];
            }
        } else {
            #pragma unroll
            for (int c = 0; c < 8; ++c) h[c] = 0.f;
        }

        // 8 lane-private dot partials (rows j), 8 independent fma chains
        float d[8];
        #pragma unroll
        for (int j = 0; j < 8; ++j) {
            float a = w[j][0] * h[0];
            a = fmaf(w[j][1], h[1], a);
            a = fmaf(w[j][2], h[2], a);
            a = fmaf(w[j][3], h[3], a);
            a = fmaf(w[j][4], h[4], a);
            a = fmaf(w[j][5], h[5], a);
            a = fmaf(w[j][6], h[6], a);
            a = fmaf(w[j][7], h[7], a);
            d[j] = a;
        }
        // butterfly reduce across 64 lanes for all 8 dots
        #pragma unroll
        for (int off = 32; off > 0; off >>= 1) {
            #pragma unroll
            for (int j = 0; j < 8; ++j) d[j] += __shfl_xor(d[j], off, 64);
        }

        if (lane < 2) {
            float zi = z0 + d[lane * 4 + 0];
            float zf = z1 + d[lane * 4 + 1];
            float zg = z2 + d[lane * 4 + 2];
            float zo = z3 + d[lane * 4 + 3];
            float ig = sigm(zi), fg = sigm(zf), gg = tanh_fast(zg), og = sigm(zo);
            cval = fg * cval + ig * gg;
            float hv = og * tanh_fast(cval);
            const size_t oidx = (size_t)t * (2 * HID) + colOff + Ub + lane;
            unsigned long long pk = ((unsigned long long)(tagBase + (unsigned)s) << 32)
                                  | (unsigned long long)__float_as_uint(hv);
            __hip_atomic_store(Hpair + oidx, pk, __ATOMIC_RELAXED, __HIP_MEMORY_SCOPE_AGENT);
            Hout[oidx] = hv;   // plain fp32 for downstream GEMMs
        }
    }
}

// ---------------------------------------------------------------- pairwise MLP scores
__global__ __launch_bounds__(256)
void pairwise_kernel(const float* __restrict__ Ah, const float* __restrict__ Bd,
                     const float* __restrict__ w2, const float* __restrict__ b2,
                     float* __restrict__ out) {
    __shared__ __align__(16) float at[16 * 260];
    __shared__ __align__(16) float bt[16 * 260];
    __shared__ __align__(16) float wl[256];
    const int tid = threadIdx.x;
    const int i0 = blockIdx.y * 16, j0 = blockIdx.x * 16;
    for (int u = tid; u < 16 * 256; u += 256) {
        int r = u >> 8, m = u & 255;
        at[r * 260 + m] = Ah[(size_t)(i0 + r) * 256 + m];
        bt[r * 260 + m] = Bd[(size_t)(j0 + r) * 256 + m];
    }
    wl[tid] = w2[tid];
    __syncthreads();
    const int tj = tid & 15, ti = tid >> 4;
    float acc = b2[0];
    #pragma unroll 2
    for (int m = 0; m < 256; m += 4) {
        float4 a4 = *(const float4*)&at[ti * 260 + m];
        float4 b4 = *(const float4*)&bt[tj * 260 + m];
        float4 w4 = *(const float4*)&wl[m];
        acc += tanh_fast(a4.x + b4.x) * w4.x;
        acc += tanh_fast(a4.y + b4.y) * w4.y;
        acc += tanh_fast(a4.z + b4.z) * w4.z;
        acc += tanh_fast(a4.w + b4.w) * w4.w;
    }
    out[(size_t)(i0 + ti) * 1024 + (j0 + tj)] = acc;
}

// ---------------------------------------------------------------- launch
extern "C" void kernel_launch(void* const* d_in, const int* in_sizes, int n_in,
                              void* d_out, int out_size, void* d_ws, size_t ws_size,
                              hipStream_t stream) {
    const int*   wi    = (const int*)  d_in[0];
    const int*   pi    = (const int*)  d_in[1];
    const float* we    = (const float*)d_in[2];
    const float* pe    = (const float*)d_in[3];
    const float* wih0f = (const float*)d_in[4];
    const float* whh0f = (const float*)d_in[5];
    const float* b0f   = (const float*)d_in[6];
    const float* wih0r = (const float*)d_in[7];
    const float* whh0r = (const float*)d_in[8];
    const float* b0r   = (const float*)d_in[9];
    const float* wih1f = (const float*)d_in[10];
    const float* whh1f = (const float*)d_in[11];
    const float* b1f   = (const float*)d_in[12];
    const float* wih1r = (const float*)d_in[13];
    const float* whh1r = (const float*)d_in[14];
    const float* b1r   = (const float*)d_in[15];
    const float* W1    = (const float*)d_in[16];
    const float* bmlp1 = (const float*)d_in[17];
    const float* w2    = (const float*)d_in[18];
    const float* b2    = (const float*)d_in[19];
    float* out = (float*)d_out;

    char* wsb = (char*)d_ws;
    float* x  = (float*)(wsb + 512);          // 1024*400
    float* zA = x  + (size_t)1024 * 400;      // 1024*2048
    float* zB = zA + (size_t)1024 * 2048;     // 1024*2048
    float* h0 = zB + (size_t)1024 * 2048;     // 1024*1024
    float* h1 = h0 + (size_t)1024 * 1024;     // 1024*1024
    float* aH = h1 + (size_t)1024 * 1024;     // 1024*256
    float* bD = aH + (size_t)1024 * 256;      // 1024*256
    unsigned long long* Hpair = (unsigned long long*)(bD + (size_t)1024 * 256); // 1024*1024 u64

    embed_kernel<<<dim3(1024), dim3(128), 0, stream>>>(wi, pi, we, pe, x);

    // layer-0 input projections: [1024,400] @ [2048,400]^T
    gemm_bias<<<dim3(32, 16), dim3(256), 0, stream>>>(x, wih0f, b0f, zA, 1024, 2048, 400, 400, 400, 2048);
    gemm_bias<<<dim3(32, 16), dim3(256), 0, stream>>>(x, wih0r, b0r, zB, 1024, 2048, 400, 400, 400, 2048);

    lstm_layer<<<dim3(64), dim3(512), 0, stream>>>(zA, zB, whh0f, whh0r, Hpair, h0, 1u);

    // layer-1 input projections: [1024,1024] @ [2048,1024]^T
    gemm_bias<<<dim3(32, 16), dim3(256), 0, stream>>>(h0, wih1f, b1f, zA, 1024, 2048, 1024, 1024, 1024, 2048);
    gemm_bias<<<dim3(32, 16), dim3(256), 0, stream>>>(h0, wih1r, b1r, zB, 1024, 2048, 1024, 1024, 1024, 2048);

    lstm_layer<<<dim3(64), dim3(512), 0, stream>>>(zA, zB, whh1f, whh1r, Hpair, h1, 8192u);

    // head/dep projections: [1024,1024] @ [256,1024]^T (bmlp1 folded into aH)
    gemm_bias<<<dim3(4, 16), dim3(256), 0, stream>>>(h1, W1,        bmlp1,   aH, 1024, 256, 1024, 1024, 2048, 256);
    gemm_bias<<<dim3(4, 16), dim3(256), 0, stream>>>(h1, W1 + 1024, nullptr, bD, 1024, 256, 1024, 1024, 2048, 256);

    pairwise_kernel<<<dim3(64, 64), dim3(256), 0, stream>>>(aH, bD, w2, b2, out);
}